// Round 25
// baseline (357.864 us; speedup 1.0000x reference)
//
#include <hip/hip_runtime.h>
#include <hip/hip_bf16.h>

#define DIMC 192
#define LTOT 3136

using bf16x8 = __attribute__((ext_vector_type(8))) short;
using f32x4  = __attribute__((ext_vector_type(4))) float;

static __device__ __forceinline__ unsigned short f2bf(float f) {
  unsigned u = __builtin_bit_cast(unsigned, f);
  u = (u + 0x7FFFu + ((u >> 16) & 1u)) >> 16;
  return (unsigned short)u;
}
static __device__ __forceinline__ float bf2f(unsigned short u) {
  unsigned v = ((unsigned)u) << 16;
  return __builtin_bit_cast(float, v);
}
static __device__ __forceinline__ int iabs(int a) { return a < 0 ? -a : a; }

static __device__ __forceinline__ void gload16(const unsigned short* g, unsigned short* lds) {
  __builtin_amdgcn_global_load_lds(
      (const __attribute__((address_space(1))) void*)g,
      (__attribute__((address_space(3))) void*)lds, 16, 0, 0);
}

// ---- prep: weights -> bf16 W^T [Npad][K]; conv w; BN fold ----
__global__ __launch_bounds__(256) void prep_k(
    const float* __restrict__ qkv_w, const float* __restrict__ proj_w,
    const float* __restrict__ fc1_w, const float* __restrict__ fc2_w,
    const float* __restrict__ conv_w,
    const float* __restrict__ bn_g, const float* __restrict__ bn_b,
    const float* __restrict__ bn_m, const float* __restrict__ bn_v,
    unsigned short* __restrict__ qkvT, unsigned short* __restrict__ projT,
    unsigned short* __restrict__ fc1T, unsigned short* __restrict__ fc2T,
    float* __restrict__ convT, float* __restrict__ bnsc, float* __restrict__ bnsh)
{
  int idx = blockIdx.x * 256 + threadIdx.x;
  if (idx < 122880) { int n = idx / 192, k = idx % 192;
    qkvT[idx] = (n < 576) ? f2bf(qkv_w[k * 576 + n]) : 0; return; }
  idx -= 122880;
  if (idx < 49152)  { int n = idx / 192, k = idx % 192;
    projT[idx] = (n < 192) ? f2bf(proj_w[k * 192 + n]) : 0; return; }
  idx -= 49152;
  if (idx < 147456) { int n = idx / 192, k = idx % 192;
    fc1T[idx] = f2bf(fc1_w[k * 768 + n]); return; }
  idx -= 147456;
  if (idx < 196608) { int n = idx / 768, k = idx % 768;
    fc2T[idx] = (n < 192) ? f2bf(fc2_w[k * 192 + n]) : 0; return; }
  idx -= 196608;
  if (idx < 1728)   { int tap = idx / 192, c = idx % 192; convT[idx] = conv_w[c * 9 + tap]; return; }
  idx -= 1728;
  if (idx < 192) {
    float s = bn_g[idx] * rsqrtf(bn_v[idx] + 1e-5f);
    bnsc[idx] = s; bnsh[idx] = bn_b[idx] - bn_m[idx] * s;
  }
}

// ---- qkv GEMM with fused LN1 v2 + setprio around MFMA cluster ----
__global__ __launch_bounds__(256) void qkvg_k(
    const float* __restrict__ x, const float* __restrict__ ln_g, const float* __restrict__ ln_b,
    const unsigned short* __restrict__ qkvT,
    const float* __restrict__ qkv_b, unsigned short* __restrict__ qkv)
{
  __shared__ unsigned short LB[12288];   // LN'd A [64][192] swz; then W chunk buffer
  const int tid = threadIdx.x;
  const int l = tid & 63, wv = tid >> 6;
  const int u = l >> 4, ll = l & 15;
  const int m0 = blockIdx.x * 64;

  // phase A: LN1 + window gather, 4 threads per row (parallel stats)
  {
    const int row = tid >> 2, part = tid & 3;
    const int m = m0 + row;
    const int w = m / 49, t = m % 49;
    const int bb = w >> 6, win = w & 63;
    const int lpix = ((win >> 3) * 7 + t / 7) * 56 + (win & 7) * 7 + t % 7;
    const float* rowp = x + ((size_t)bb * LTOT + lpix) * DIMC + part * 48;
    float4 v[12];
    float s = 0.f, ss = 0.f;
    #pragma unroll
    for (int i = 0; i < 12; ++i) {
      v[i] = *(const float4*)(rowp + i * 4);
      s  += v[i].x + v[i].y + v[i].z + v[i].w;
      ss += v[i].x * v[i].x + v[i].y * v[i].y + v[i].z * v[i].z + v[i].w * v[i].w;
    }
    s += __shfl_xor(s, 1); ss += __shfl_xor(ss, 1);
    s += __shfl_xor(s, 2); ss += __shfl_xor(ss, 2);
    float mean = s * (1.f / 192.f);
    float rstd = rsqrtf(ss * (1.f / 192.f) - mean * mean + 1e-5f);
    const float* gp = ln_g + part * 48;
    const float* bp = ln_b + part * 48;
    #pragma unroll
    for (int i = 0; i < 12; ++i) {
      float4 gg = *(const float4*)(gp + i * 4);
      float4 bb4 = *(const float4*)(bp + i * 4);
      ushort4 o;
      o.x = f2bf((v[i].x - mean) * rstd * gg.x + bb4.x);
      o.y = f2bf((v[i].y - mean) * rstd * gg.y + bb4.y);
      o.z = f2bf((v[i].z - mean) * rstd * gg.z + bb4.z);
      o.w = f2bf((v[i].w - mean) * rstd * gg.w + bb4.w);
      int cbyte = part * 96 + i * 8;
      *(ushort4*)((char*)LB + row * 384 + (cbyte ^ ((row & 7) << 4))) = o;
    }
  }
  __syncthreads();   // A rows ready in LB

  // phase B: areg fragments from LB
  bf16x8 areg[6];
  #pragma unroll
  for (int kk = 0; kk < 6; ++kk) {
    int cb = (kk * 64 + u * 16) ^ ((ll & 7) << 4);
    areg[kk] = *(const bf16x8*)((const char*)LB + (wv * 16 + ll) * 384 + cb);
  }

  // chunk loop: LB reused as W buffer
  for (int c = 0; c < 9; ++c) {
    __syncthreads();
    const char* Wg = (const char*)(qkvT + (size_t)c * 64 * 192);
    #pragma unroll
    for (int i = 0; i < 6; ++i) {
      int ob = i * 4096 + tid * 16;
      int r = ob / 384, cc = ob % 384;
      int cs = cc ^ ((r & 7) << 4);
      gload16((const unsigned short*)(Wg + r * 384 + cs), &LB[ob >> 1]);
    }
    __syncthreads();
    f32x4 p1[4] = {};
    __builtin_amdgcn_s_setprio(1);
    #pragma unroll
    for (int kk = 0; kk < 6; ++kk) {
      int cb = (kk * 64 + u * 16) ^ ((ll & 7) << 4);
      #pragma unroll
      for (int nf = 0; nf < 4; ++nf) {
        bf16x8 bfr = *(const bf16x8*)((const char*)LB + (nf * 16 + ll) * 384 + cb);
        p1[nf] = __builtin_amdgcn_mfma_f32_16x16x32_bf16(areg[kk], bfr, p1[nf], 0, 0, 0);
      }
    }
    __builtin_amdgcn_s_setprio(0);
    #pragma unroll
    for (int nf = 0; nf < 4; ++nf)
    #pragma unroll
    for (int r = 0; r < 4; ++r) {
      int m = m0 + wv * 16 + u * 4 + r;
      int n = c * 64 + nf * 16 + ll;
      qkv[(size_t)m * 576 + n] = f2bf(p1[nf][r] + qkv_b[n]);
    }
  }
}

// ---- attention + proj + residual: one block/window, 4 waves (proven) ----
__global__ __launch_bounds__(256) void attnp_k(
    const unsigned short* __restrict__ qkv, const float* __restrict__ attn_bias,
    const unsigned short* __restrict__ projT, const float* __restrict__ proj_b,
    const float* __restrict__ x, unsigned short* __restrict__ x1b)
{
  __shared__ unsigned short Qs[2560];
  __shared__ unsigned short Ks[2560];
  __shared__ unsigned short Vt[2304];
  __shared__ unsigned short Ps[4608];
  __shared__ float bias_s[52];
  const int tid = threadIdx.x;
  const int l = tid & 63, wv = tid >> 6;
  const int u = l >> 4, ll = l & 15;
  const int w = blockIdx.x, b = w >> 6, win = w & 63;
  const f32x4 fz = {0.f, 0.f, 0.f, 0.f};

  for (int i = tid; i < 15 * 40; i += 256) {
    Qs[(49 + i / 40) * 40 + i % 40] = 0;
    Ks[(49 + i / 40) * 40 + i % 40] = 0;
  }
  for (int i = tid; i < 32 * 15; i += 256) Vt[(i / 15) * 72 + 49 + i % 15] = 0;

  f32x4 pacc[4][3] = {};

  for (int h = 0; h < 6; ++h) {
    __syncthreads();
    if (tid < 49) bias_s[tid] = attn_bias[h * 49 + tid];
    #pragma unroll
    for (int it = 0; it < 3; ++it) {
      int idx = tid + it * 256;
      if (idx < 588) {
        int row = idx / 12, g = idx % 12;
        int4 v = *(const int4*)&qkv[((size_t)w * 49 + row) * 576 + h * 96 + g * 8];
        if (g < 4) *(int4*)&Qs[row * 40 + g * 8] = v;
        else if (g < 8) *(int4*)&Ks[row * 40 + (g - 4) * 8] = v;
        else {
          union { int4 v4; unsigned short us[8]; } uu; uu.v4 = v;
          int d0 = (g - 8) * 8;
          #pragma unroll
          for (int e = 0; e < 8; ++e) Vt[(d0 + e) * 72 + row] = uu.us[e];
        }
      }
    }
    __syncthreads();

    {
      const int qr = wv * 16 + ll;
      const int qi = qr > 48 ? 48 : qr;
      bf16x8 qf = *(const bf16x8*)&Qs[(wv * 16 + ll) * 40 + u * 8];
      f32x4 sc[4];
      #pragma unroll
      for (int kt = 0; kt < 4; ++kt) {
        bf16x8 kf = *(const bf16x8*)&Ks[(kt * 16 + ll) * 40 + u * 8];
        sc[kt] = __builtin_amdgcn_mfma_f32_16x16x32_bf16(kf, qf, fz, 0, 0, 0);
      }
      float sv[4][4];
      float mx = -1e30f;
      #pragma unroll
      for (int kt = 0; kt < 4; ++kt)
        #pragma unroll
        for (int r = 0; r < 4; ++r) {
          int kr = kt * 16 + u * 4 + r;
          float val = -1e30f;
          if (kr < 49)
            val = sc[kt][r] * 0.17677669529663689f +
                  bias_s[iabs(qi / 7 - kr / 7) * 7 + iabs(qi % 7 - kr % 7)];
          sv[kt][r] = val;
          mx = fmaxf(mx, val);
        }
      mx = fmaxf(mx, __shfl_xor(mx, 16));
      mx = fmaxf(mx, __shfl_xor(mx, 32));
      float sum = 0.f;
      #pragma unroll
      for (int kt = 0; kt < 4; ++kt)
        #pragma unroll
        for (int r = 0; r < 4; ++r) {
          float p = __expf(sv[kt][r] - mx);
          sv[kt][r] = p; sum += p;
        }
      sum += __shfl_xor(sum, 16);
      sum += __shfl_xor(sum, 32);
      float inv = 1.f / sum;
      #pragma unroll
      for (int kt = 0; kt < 4; ++kt)
        #pragma unroll
        for (int r = 0; r < 4; ++r)
          Ps[(wv * 16 + ll) * 72 + kt * 16 + u * 4 + r] = f2bf(sv[kt][r] * inv);
    }
    __syncthreads();

    {
      f32x4 oa[2] = {fz, fz};
      #pragma unroll
      for (int kk = 0; kk < 2; ++kk) {
        bf16x8 pf = *(const bf16x8*)&Ps[(wv * 16 + ll) * 72 + kk * 32 + u * 8];
        #pragma unroll
        for (int nt = 0; nt < 2; ++nt) {
          bf16x8 vf = *(const bf16x8*)&Vt[(nt * 16 + ll) * 72 + kk * 32 + u * 8];
          oa[nt] = __builtin_amdgcn_mfma_f32_16x16x32_bf16(pf, vf, oa[nt], 0, 0, 0);
        }
      }
      #pragma unroll
      for (int nt = 0; nt < 2; ++nt)
        #pragma unroll
        for (int r = 0; r < 4; ++r)
          Qs[(wv * 16 + u * 4 + r) * 40 + nt * 16 + ll] = f2bf(oa[nt][r]);
    }
    __syncthreads();

    {
      bf16x8 af[4], bfr[3];
      #pragma unroll
      for (int mt = 0; mt < 4; ++mt)
        af[mt] = *(const bf16x8*)&Qs[(mt * 16 + ll) * 40 + u * 8];
      #pragma unroll
      for (int nf = 0; nf < 3; ++nf)
        bfr[nf] = *(const bf16x8*)&projT[(size_t)(wv * 48 + nf * 16 + ll) * 192 + h * 32 + u * 8];
      #pragma unroll
      for (int mt = 0; mt < 4; ++mt)
        #pragma unroll
        for (int nf = 0; nf < 3; ++nf)
          pacc[mt][nf] = __builtin_amdgcn_mfma_f32_16x16x32_bf16(af[mt], bfr[nf], pacc[mt][nf], 0, 0, 0);
    }
  }

  #pragma unroll
  for (int mt = 0; mt < 4; ++mt)
  #pragma unroll
  for (int r = 0; r < 4; ++r) {
    int m = mt * 16 + u * 4 + r;
    if (m < 49) {
      int lpix = ((win >> 3) * 7 + m / 7) * 56 + (win & 7) * 7 + m % 7;
      size_t base = ((size_t)b * LTOT + lpix) * DIMC;
      #pragma unroll
      for (int nf = 0; nf < 3; ++nf) {
        int n = wv * 48 + nf * 16 + ll;
        float val = pacc[mt][nf][r] + proj_b[n] + x[base + n];
        x1b[base + n] = f2bf(val);
      }
    }
  }
}

// ---- fused MLP v12: v10 + setprio around MFMA clusters ----
__global__ __launch_bounds__(256) void fmlp_k(
    const unsigned short* __restrict__ h2, const unsigned short* __restrict__ fc1T,
    const float* __restrict__ fc1_b, const unsigned short* __restrict__ fc2T,
    const float* __restrict__ fc2_b, const unsigned short* __restrict__ x2,
    float* __restrict__ out)
{
  __shared__ unsigned short W1[6144];
  __shared__ unsigned short W2[6144];
  __shared__ unsigned short P[2048];
  const int tid = threadIdx.x;
  const int l = tid & 63, wv = tid >> 6;
  const int u = l >> 4, ll = l & 15;
  const int m0 = blockIdx.x * 64;
  f32x4 acc[12] = {};

  bf16x8 areg[6];
  {
    const unsigned short* arow = h2 + (size_t)(m0 + wv * 16 + ll) * 192;
    #pragma unroll
    for (int kk = 0; kk < 6; ++kk)
      areg[kk] = *(const bf16x8*)(arow + kk * 32 + u * 8);
  }

  for (int c = 0; c < 24; ++c) {
    if (c) __syncthreads();
    const char* W1g = (const char*)(fc1T + (size_t)c * 32 * 192);
    #pragma unroll
    for (int i = 0; i < 3; ++i) {
      int ob = i * 4096 + tid * 16;
      int r = ob / 384, cc = ob % 384;
      int cs = cc ^ ((r & 7) << 4);
      gload16((const unsigned short*)(W1g + r * 384 + cs), &W1[ob >> 1]);
    }
    #pragma unroll
    for (int i = 0; i < 3; ++i) {
      int unit = i * 256 + tid;
      int r = unit >> 2, q = unit & 3;
      int4 vv = *(const int4*)&fc2T[(size_t)r * 768 + c * 32 + q * 8];
      *(int4*)((char*)W2 + r * 64 + ((q * 16) ^ (((r >> 1) & 3) << 4))) = vv;
    }
    __syncthreads();

    {
      f32x4 p1[2] = {};
      __builtin_amdgcn_s_setprio(1);
      #pragma unroll
      for (int kk = 0; kk < 6; ++kk) {
        int cb = (kk * 64 + u * 16) ^ ((ll & 7) << 4);
        #pragma unroll
        for (int nf = 0; nf < 2; ++nf) {
          bf16x8 bfr = *(const bf16x8*)((const char*)W1 + (nf * 16 + ll) * 384 + cb);
          p1[nf] = __builtin_amdgcn_mfma_f32_16x16x32_bf16(areg[kk], bfr, p1[nf], 0, 0, 0);
        }
      }
      __builtin_amdgcn_s_setprio(0);
      #pragma unroll
      for (int nf = 0; nf < 2; ++nf)
      #pragma unroll
      for (int r = 0; r < 4; ++r) {
        int mrow = wv * 16 + u * 4 + r;
        int n = nf * 16 + ll;
        float v = p1[nf][r] + fc1_b[c * 32 + n];
        float gl = v / (1.f + __expf(-1.702f * v));
        *(unsigned short*)((char*)P + mrow * 64 + ((n * 2) ^ (((mrow >> 1) & 3) << 4))) = f2bf(gl);
      }
    }
    {
      bf16x8 af2 = *(const bf16x8*)((const char*)P + (wv * 16 + ll) * 64 +
                                    ((u * 16) ^ (((ll >> 1) & 3) << 4)));
      __builtin_amdgcn_s_setprio(1);
      #pragma unroll
      for (int nt = 0; nt < 12; ++nt) {
        bf16x8 bfr = *(const bf16x8*)((const char*)W2 + (nt * 16 + ll) * 64 +
                                      ((u * 16) ^ (((ll >> 1) & 3) << 4)));
        acc[nt] = __builtin_amdgcn_mfma_f32_16x16x32_bf16(af2, bfr, acc[nt], 0, 0, 0);
      }
      __builtin_amdgcn_s_setprio(0);
    }
  }
  #pragma unroll
  for (int nt = 0; nt < 12; ++nt)
  #pragma unroll
  for (int r = 0; r < 4; ++r) {
    int m = m0 + wv * 16 + u * 4 + r;
    int n = nt * 16 + ll;
    size_t o = (size_t)m * 192 + n;
    out[o] = acc[nt][r] + fc2_b[n] + bf2f(x2[o]);
  }
}

// ---- depthwise 3x3 conv v3 (proven): horizontal pixel-quad ----
__global__ __launch_bounds__(256) void conv_k(
    const unsigned short* __restrict__ x1b, const float* __restrict__ wT,
    const float* __restrict__ bnsc, const float* __restrict__ bnsh,
    const float* __restrict__ g2, const float* __restrict__ b2,
    unsigned short* __restrict__ x2, unsigned short* __restrict__ h2)
{
  const int bid = blockIdx.x;
  const int swz = (bid & 7) * 784 + (bid >> 3);
  const int grp = threadIdx.x >> 6, l = threadIdx.x & 63;
  const int qq = swz * 4 + grp;
  const int b = qq / 784, rem = qq % 784;
  const int pix0 = rem * 4;
  const int i = pix0 / 56, j = pix0 % 56;
  const bool act = l < 48;
  const int c = l * 4;
  float4 a[4];
  #pragma unroll
  for (int p = 0; p < 4; ++p) a[p] = make_float4(0.f, 0.f, 0.f, 0.f);
  if (act) {
    #pragma unroll
    for (int di = -1; di <= 1; ++di) {
      int ni = i + di;
      if (ni < 0 || ni >= 56) continue;
      #pragma unroll
      for (int djx = 0; djx < 6; ++djx) {
        int nj = j - 1 + djx;
        float4 vv = make_float4(0.f, 0.f, 0.f, 0.f);
        if (nj >= 0 && nj < 56) {
          ushort4 sv = *(const ushort4*)&x1b[((size_t)b * LTOT + ni * 56 + nj) * DIMC + c];
          vv.x = bf2f(sv.x); vv.y = bf2f(sv.y); vv.z = bf2f(sv.z); vv.w = bf2f(sv.w);
        }
        #pragma unroll
        for (int p = 0; p < 4; ++p) {
          int dj = djx - p;
          if (dj >= 0 && dj <= 2) {
            float4 w = *(const float4*)&wT[((di + 1) * 3 + dj) * DIMC + c];
            a[p].x += vv.x * w.x; a[p].y += vv.y * w.y;
            a[p].z += vv.z * w.z; a[p].w += vv.w * w.w;
          }
        }
      }
    }
    float4 s4 = *(const float4*)&bnsc[c];
    float4 h4 = *(const float4*)&bnsh[c];
    #pragma unroll
    for (int p = 0; p < 4; ++p) {
      a[p].x = a[p].x * s4.x + h4.x; a[p].y = a[p].y * s4.y + h4.y;
      a[p].z = a[p].z * s4.z + h4.z; a[p].w = a[p].w * s4.w + h4.w;
      ushort4 xv;
      xv.x = f2bf(a[p].x); xv.y = f2bf(a[p].y); xv.z = f2bf(a[p].z); xv.w = f2bf(a[p].w);
      *(ushort4*)&x2[((size_t)b * LTOT + i * 56 + j + p) * DIMC + c] = xv;
    }
  }
  #pragma unroll
  for (int p = 0; p < 4; ++p) {
    float s = act ? a[p].x + a[p].y + a[p].z + a[p].w : 0.f;
    float ss = act ? a[p].x * a[p].x + a[p].y * a[p].y + a[p].z * a[p].z + a[p].w * a[p].w : 0.f;
    #pragma unroll
    for (int off = 1; off < 64; off <<= 1) { s += __shfl_xor(s, off); ss += __shfl_xor(ss, off); }
    float mean = s * (1.f / 192.f);
    float rstd = rsqrtf(ss * (1.f / 192.f) - mean * mean + 1e-5f);
    if (act) {
      float4 gg = *(const float4*)&g2[c];
      float4 bb = *(const float4*)&b2[c];
      ushort4 ov;
      ov.x = f2bf((a[p].x - mean) * rstd * gg.x + bb.x);
      ov.y = f2bf((a[p].y - mean) * rstd * gg.y + bb.y);
      ov.z = f2bf((a[p].z - mean) * rstd * gg.z + bb.z);
      ov.w = f2bf((a[p].w - mean) * rstd * gg.w + bb.w);
      *(ushort4*)&h2[((size_t)b * LTOT + i * 56 + j + p) * DIMC + c] = ov;
    }
  }
}

extern "C" void kernel_launch(void* const* d_in, const int* in_sizes, int n_in,
                              void* d_out, int out_size, void* d_ws, size_t ws_size,
                              hipStream_t stream) {
  const float* x      = (const float*)d_in[0];
  const float* ln1_g  = (const float*)d_in[1];
  const float* ln1_b  = (const float*)d_in[2];
  const float* qkv_w  = (const float*)d_in[3];
  const float* qkv_b  = (const float*)d_in[4];
  const float* proj_w = (const float*)d_in[5];
  const float* proj_b = (const float*)d_in[6];
  const float* attn_b = (const float*)d_in[7];
  const float* conv_w = (const float*)d_in[8];
  const float* bn_g   = (const float*)d_in[9];
  const float* bn_b   = (const float*)d_in[10];
  const float* bn_m   = (const float*)d_in[11];
  const float* bn_v   = (const float*)d_in[12];
  const float* ln2_g  = (const float*)d_in[13];
  const float* ln2_b  = (const float*)d_in[14];
  const float* fc1_w  = (const float*)d_in[15];
  const float* fc1_b  = (const float*)d_in[16];
  const float* fc2_w  = (const float*)d_in[17];
  const float* fc2_b  = (const float*)d_in[18];
  float* out = (float*)d_out;

  // workspace (155,189,248 B total — proven size):
  //  WREG [0,1MiB): converted weights
  //  A [1MiB, +115,605,504): qkv bf16 [M][576] -> (x2 @A+0, h2 @A+38.5MB after qkv dead)
  //  B [A_end, +38,535,168): x1b
  const size_t AOFF = 1048576, BOFF = AOFF + 115605504;
  const size_t NEEDED = BOFF + 38535168;
  if (ws_size < NEEDED) return;

  char* ws = (char*)d_ws;
  unsigned short* qkvT  = (unsigned short*)(ws);
  unsigned short* projT = (unsigned short*)(ws + 245760);
  unsigned short* fc1T  = (unsigned short*)(ws + 344064);
  unsigned short* fc2T  = (unsigned short*)(ws + 638976);
  float*          convT = (float*)(ws + 1032192);
  float*          bnsc  = (float*)(ws + 1039104);
  float*          bnsh  = (float*)(ws + 1039872);

  unsigned short* qkv = (unsigned short*)(ws + AOFF);
  unsigned short* x2  = (unsigned short*)(ws + AOFF);
  unsigned short* h2  = (unsigned short*)(ws + AOFF + 38535168);
  unsigned short* x1b = (unsigned short*)(ws + BOFF);

  prep_k<<<2024, 256, 0, stream>>>(qkv_w, proj_w, fc1_w, fc2_w, conv_w,
                                   bn_g, bn_b, bn_m, bn_v,
                                   qkvT, projT, fc1T, fc2T, convT, bnsc, bnsh);
  qkvg_k<<<1568, 256, 0, stream>>>(x, ln1_g, ln1_b, qkvT, qkv_b, qkv);
  attnp_k<<<2048, 256, 0, stream>>>(qkv, attn_b, projT, proj_b, x, x1b);
  conv_k<<<6272, 256, 0, stream>>>(x1b, convT, bnsc, bnsh, ln2_g, ln2_b, x2, h2);
  fmlp_k<<<1568, 256, 0, stream>>>(h2, fc1T, fc1_b, fc2T, fc2_b, x2, out);
}

// Round 26
// 330.009 us; speedup vs baseline: 1.0844x; 1.0844x over previous
//
#include <hip/hip_runtime.h>
#include <hip/hip_bf16.h>

#define DIMC 192
#define LTOT 3136

using bf16x8 = __attribute__((ext_vector_type(8))) short;
using f32x4  = __attribute__((ext_vector_type(4))) float;

static __device__ __forceinline__ unsigned short f2bf(float f) {
  unsigned u = __builtin_bit_cast(unsigned, f);
  u = (u + 0x7FFFu + ((u >> 16) & 1u)) >> 16;
  return (unsigned short)u;
}
static __device__ __forceinline__ float bf2f(unsigned short u) {
  unsigned v = ((unsigned)u) << 16;
  return __builtin_bit_cast(float, v);
}
static __device__ __forceinline__ int iabs(int a) { return a < 0 ? -a : a; }

static __device__ __forceinline__ void gload16(const unsigned short* g, unsigned short* lds) {
  __builtin_amdgcn_global_load_lds(
      (const __attribute__((address_space(1))) void*)g,
      (__attribute__((address_space(3))) void*)lds, 16, 0, 0);
}

// ---- prep: weights -> bf16 W^T [Npad][K]; conv w; BN fold ----
__global__ __launch_bounds__(256) void prep_k(
    const float* __restrict__ qkv_w, const float* __restrict__ proj_w,
    const float* __restrict__ fc1_w, const float* __restrict__ fc2_w,
    const float* __restrict__ conv_w,
    const float* __restrict__ bn_g, const float* __restrict__ bn_b,
    const float* __restrict__ bn_m, const float* __restrict__ bn_v,
    unsigned short* __restrict__ qkvT, unsigned short* __restrict__ projT,
    unsigned short* __restrict__ fc1T, unsigned short* __restrict__ fc2T,
    float* __restrict__ convT, float* __restrict__ bnsc, float* __restrict__ bnsh)
{
  int idx = blockIdx.x * 256 + threadIdx.x;
  if (idx < 122880) { int n = idx / 192, k = idx % 192;
    qkvT[idx] = (n < 576) ? f2bf(qkv_w[k * 576 + n]) : 0; return; }
  idx -= 122880;
  if (idx < 49152)  { int n = idx / 192, k = idx % 192;
    projT[idx] = (n < 192) ? f2bf(proj_w[k * 192 + n]) : 0; return; }
  idx -= 49152;
  if (idx < 147456) { int n = idx / 192, k = idx % 192;
    fc1T[idx] = f2bf(fc1_w[k * 768 + n]); return; }
  idx -= 147456;
  if (idx < 196608) { int n = idx / 768, k = idx % 768;
    fc2T[idx] = (n < 192) ? f2bf(fc2_w[k * 192 + n]) : 0; return; }
  idx -= 196608;
  if (idx < 1728)   { int tap = idx / 192, c = idx % 192; convT[idx] = conv_w[c * 9 + tap]; return; }
  idx -= 1728;
  if (idx < 192) {
    float s = bn_g[idx] * rsqrtf(bn_v[idx] + 1e-5f);
    bnsc[idx] = s; bnsh[idx] = bn_b[idx] - bn_m[idx] * s;
  }
}

// ---- qkv GEMM with fused LN1 v2: PARALLEL stats (4 thr/row), LB stash, W reuse ----
__global__ __launch_bounds__(256) void qkvg_k(
    const float* __restrict__ x, const float* __restrict__ ln_g, const float* __restrict__ ln_b,
    const unsigned short* __restrict__ qkvT,
    const float* __restrict__ qkv_b, unsigned short* __restrict__ qkv)
{
  __shared__ unsigned short LB[12288];   // LN'd A [64][192] swz; then W chunk buffer
  const int tid = threadIdx.x;
  const int l = tid & 63, wv = tid >> 6;
  const int u = l >> 4, ll = l & 15;
  const int m0 = blockIdx.x * 64;

  // phase A: LN1 + window gather, 4 threads per row (one pass, parallel)
  {
    const int row = tid >> 2, part = tid & 3;
    const int m = m0 + row;
    const int w = m / 49, t = m % 49;
    const int bb = w >> 6, win = w & 63;
    const int lpix = ((win >> 3) * 7 + t / 7) * 56 + (win & 7) * 7 + t % 7;
    const float* rowp = x + ((size_t)bb * LTOT + lpix) * DIMC + part * 48;
    float4 v[12];
    float s = 0.f, ss = 0.f;
    #pragma unroll
    for (int i = 0; i < 12; ++i) {
      v[i] = *(const float4*)(rowp + i * 4);
      s  += v[i].x + v[i].y + v[i].z + v[i].w;
      ss += v[i].x * v[i].x + v[i].y * v[i].y + v[i].z * v[i].z + v[i].w * v[i].w;
    }
    s += __shfl_xor(s, 1); ss += __shfl_xor(ss, 1);
    s += __shfl_xor(s, 2); ss += __shfl_xor(ss, 2);
    float mean = s * (1.f / 192.f);
    float rstd = rsqrtf(ss * (1.f / 192.f) - mean * mean + 1e-5f);
    const float* gp = ln_g + part * 48;
    const float* bp = ln_b + part * 48;
    #pragma unroll
    for (int i = 0; i < 12; ++i) {
      float4 gg = *(const float4*)(gp + i * 4);
      float4 bb4 = *(const float4*)(bp + i * 4);
      ushort4 o;
      o.x = f2bf((v[i].x - mean) * rstd * gg.x + bb4.x);
      o.y = f2bf((v[i].y - mean) * rstd * gg.y + bb4.y);
      o.z = f2bf((v[i].z - mean) * rstd * gg.z + bb4.z);
      o.w = f2bf((v[i].w - mean) * rstd * gg.w + bb4.w);
      int cbyte = part * 96 + i * 8;
      *(ushort4*)((char*)LB + row * 384 + (cbyte ^ ((row & 7) << 4))) = o;
    }
  }
  __syncthreads();   // A rows ready in LB

  // phase B: areg fragments from LB (proven read pattern)
  bf16x8 areg[6];
  #pragma unroll
  for (int kk = 0; kk < 6; ++kk) {
    int cb = (kk * 64 + u * 16) ^ ((ll & 7) << 4);
    areg[kk] = *(const bf16x8*)((const char*)LB + (wv * 16 + ll) * 384 + cb);
  }

  // chunk loop: LB reused as W buffer (unconditional top barrier)
  for (int c = 0; c < 9; ++c) {
    __syncthreads();          // areg loaded / prev chunk readers done
    const char* Wg = (const char*)(qkvT + (size_t)c * 64 * 192);
    #pragma unroll
    for (int i = 0; i < 6; ++i) {
      int ob = i * 4096 + tid * 16;
      int r = ob / 384, cc = ob % 384;
      int cs = cc ^ ((r & 7) << 4);
      gload16((const unsigned short*)(Wg + r * 384 + cs), &LB[ob >> 1]);
    }
    __syncthreads();          // W chunk ready
    f32x4 p1[4] = {};
    #pragma unroll
    for (int kk = 0; kk < 6; ++kk) {
      int cb = (kk * 64 + u * 16) ^ ((ll & 7) << 4);
      #pragma unroll
      for (int nf = 0; nf < 4; ++nf) {
        bf16x8 bfr = *(const bf16x8*)((const char*)LB + (nf * 16 + ll) * 384 + cb);
        p1[nf] = __builtin_amdgcn_mfma_f32_16x16x32_bf16(areg[kk], bfr, p1[nf], 0, 0, 0);
      }
    }
    #pragma unroll
    for (int nf = 0; nf < 4; ++nf)
    #pragma unroll
    for (int r = 0; r < 4; ++r) {
      int m = m0 + wv * 16 + u * 4 + r;
      int n = c * 64 + nf * 16 + ll;
      qkv[(size_t)m * 576 + n] = f2bf(p1[nf][r] + qkv_b[n]);
    }
  }
}

// ---- attention + proj + residual: one block/window, 4 waves (proven) ----
__global__ __launch_bounds__(256) void attnp_k(
    const unsigned short* __restrict__ qkv, const float* __restrict__ attn_bias,
    const unsigned short* __restrict__ projT, const float* __restrict__ proj_b,
    const float* __restrict__ x, unsigned short* __restrict__ x1b)
{
  __shared__ unsigned short Qs[2560];
  __shared__ unsigned short Ks[2560];
  __shared__ unsigned short Vt[2304];
  __shared__ unsigned short Ps[4608];
  __shared__ float bias_s[52];
  const int tid = threadIdx.x;
  const int l = tid & 63, wv = tid >> 6;
  const int u = l >> 4, ll = l & 15;
  const int w = blockIdx.x, b = w >> 6, win = w & 63;
  const f32x4 fz = {0.f, 0.f, 0.f, 0.f};

  for (int i = tid; i < 15 * 40; i += 256) {
    Qs[(49 + i / 40) * 40 + i % 40] = 0;
    Ks[(49 + i / 40) * 40 + i % 40] = 0;
  }
  for (int i = tid; i < 32 * 15; i += 256) Vt[(i / 15) * 72 + 49 + i % 15] = 0;

  f32x4 pacc[4][3] = {};

  for (int h = 0; h < 6; ++h) {
    __syncthreads();
    if (tid < 49) bias_s[tid] = attn_bias[h * 49 + tid];
    #pragma unroll
    for (int it = 0; it < 3; ++it) {
      int idx = tid + it * 256;
      if (idx < 588) {
        int row = idx / 12, g = idx % 12;
        int4 v = *(const int4*)&qkv[((size_t)w * 49 + row) * 576 + h * 96 + g * 8];
        if (g < 4) *(int4*)&Qs[row * 40 + g * 8] = v;
        else if (g < 8) *(int4*)&Ks[row * 40 + (g - 4) * 8] = v;
        else {
          union { int4 v4; unsigned short us[8]; } uu; uu.v4 = v;
          int d0 = (g - 8) * 8;
          #pragma unroll
          for (int e = 0; e < 8; ++e) Vt[(d0 + e) * 72 + row] = uu.us[e];
        }
      }
    }
    __syncthreads();

    {
      const int qr = wv * 16 + ll;
      const int qi = qr > 48 ? 48 : qr;
      bf16x8 qf = *(const bf16x8*)&Qs[(wv * 16 + ll) * 40 + u * 8];
      f32x4 sc[4];
      #pragma unroll
      for (int kt = 0; kt < 4; ++kt) {
        bf16x8 kf = *(const bf16x8*)&Ks[(kt * 16 + ll) * 40 + u * 8];
        sc[kt] = __builtin_amdgcn_mfma_f32_16x16x32_bf16(kf, qf, fz, 0, 0, 0);
      }
      float sv[4][4];
      float mx = -1e30f;
      #pragma unroll
      for (int kt = 0; kt < 4; ++kt)
        #pragma unroll
        for (int r = 0; r < 4; ++r) {
          int kr = kt * 16 + u * 4 + r;
          float val = -1e30f;
          if (kr < 49)
            val = sc[kt][r] * 0.17677669529663689f +
                  bias_s[iabs(qi / 7 - kr / 7) * 7 + iabs(qi % 7 - kr % 7)];
          sv[kt][r] = val;
          mx = fmaxf(mx, val);
        }
      mx = fmaxf(mx, __shfl_xor(mx, 16));
      mx = fmaxf(mx, __shfl_xor(mx, 32));
      float sum = 0.f;
      #pragma unroll
      for (int kt = 0; kt < 4; ++kt)
        #pragma unroll
        for (int r = 0; r < 4; ++r) {
          float p = __expf(sv[kt][r] - mx);
          sv[kt][r] = p; sum += p;
        }
      sum += __shfl_xor(sum, 16);
      sum += __shfl_xor(sum, 32);
      float inv = 1.f / sum;
      #pragma unroll
      for (int kt = 0; kt < 4; ++kt)
        #pragma unroll
        for (int r = 0; r < 4; ++r)
          Ps[(wv * 16 + ll) * 72 + kt * 16 + u * 4 + r] = f2bf(sv[kt][r] * inv);
    }
    __syncthreads();

    {
      f32x4 oa[2] = {fz, fz};
      #pragma unroll
      for (int kk = 0; kk < 2; ++kk) {
        bf16x8 pf = *(const bf16x8*)&Ps[(wv * 16 + ll) * 72 + kk * 32 + u * 8];
        #pragma unroll
        for (int nt = 0; nt < 2; ++nt) {
          bf16x8 vf = *(const bf16x8*)&Vt[(nt * 16 + ll) * 72 + kk * 32 + u * 8];
          oa[nt] = __builtin_amdgcn_mfma_f32_16x16x32_bf16(pf, vf, oa[nt], 0, 0, 0);
        }
      }
      #pragma unroll
      for (int nt = 0; nt < 2; ++nt)
        #pragma unroll
        for (int r = 0; r < 4; ++r)
          Qs[(wv * 16 + u * 4 + r) * 40 + nt * 16 + ll] = f2bf(oa[nt][r]);
    }
    __syncthreads();

    {
      bf16x8 af[4], bfr[3];
      #pragma unroll
      for (int mt = 0; mt < 4; ++mt)
        af[mt] = *(const bf16x8*)&Qs[(mt * 16 + ll) * 40 + u * 8];
      #pragma unroll
      for (int nf = 0; nf < 3; ++nf)
        bfr[nf] = *(const bf16x8*)&projT[(size_t)(wv * 48 + nf * 16 + ll) * 192 + h * 32 + u * 8];
      #pragma unroll
      for (int mt = 0; mt < 4; ++mt)
        #pragma unroll
        for (int nf = 0; nf < 3; ++nf)
          pacc[mt][nf] = __builtin_amdgcn_mfma_f32_16x16x32_bf16(af[mt], bfr[nf], pacc[mt][nf], 0, 0, 0);
    }
  }

  #pragma unroll
  for (int mt = 0; mt < 4; ++mt)
  #pragma unroll
  for (int r = 0; r < 4; ++r) {
    int m = mt * 16 + u * 4 + r;
    if (m < 49) {
      int lpix = ((win >> 3) * 7 + m / 7) * 56 + (win & 7) * 7 + m % 7;
      size_t base = ((size_t)b * LTOT + lpix) * DIMC;
      #pragma unroll
      for (int nf = 0; nf < 3; ++nf) {
        int n = wv * 48 + nf * 16 + ll;
        float val = pacc[mt][nf][r] + proj_b[n] + x[base + n];
        x1b[base + n] = f2bf(val);
      }
    }
  }
}

// ---- fused MLP v10 (proven best): N-chunk 32, corrected keys, fast GELU ----
__global__ __launch_bounds__(256) void fmlp_k(
    const unsigned short* __restrict__ h2, const unsigned short* __restrict__ fc1T,
    const float* __restrict__ fc1_b, const unsigned short* __restrict__ fc2T,
    const float* __restrict__ fc2_b, const unsigned short* __restrict__ x2,
    float* __restrict__ out)
{
  __shared__ unsigned short W1[6144];
  __shared__ unsigned short W2[6144];
  __shared__ unsigned short P[2048];
  const int tid = threadIdx.x;
  const int l = tid & 63, wv = tid >> 6;
  const int u = l >> 4, ll = l & 15;
  const int m0 = blockIdx.x * 64;
  f32x4 acc[12] = {};

  bf16x8 areg[6];
  {
    const unsigned short* arow = h2 + (size_t)(m0 + wv * 16 + ll) * 192;
    #pragma unroll
    for (int kk = 0; kk < 6; ++kk)
      areg[kk] = *(const bf16x8*)(arow + kk * 32 + u * 8);
  }

  for (int c = 0; c < 24; ++c) {
    if (c) __syncthreads();
    const char* W1g = (const char*)(fc1T + (size_t)c * 32 * 192);
    #pragma unroll
    for (int i = 0; i < 3; ++i) {
      int ob = i * 4096 + tid * 16;
      int r = ob / 384, cc = ob % 384;
      int cs = cc ^ ((r & 7) << 4);
      gload16((const unsigned short*)(W1g + r * 384 + cs), &W1[ob >> 1]);
    }
    #pragma unroll
    for (int i = 0; i < 3; ++i) {
      int unit = i * 256 + tid;
      int r = unit >> 2, q = unit & 3;
      int4 vv = *(const int4*)&fc2T[(size_t)r * 768 + c * 32 + q * 8];
      *(int4*)((char*)W2 + r * 64 + ((q * 16) ^ (((r >> 1) & 3) << 4))) = vv;
    }
    __syncthreads();

    {
      f32x4 p1[2] = {};
      #pragma unroll
      for (int kk = 0; kk < 6; ++kk) {
        int cb = (kk * 64 + u * 16) ^ ((ll & 7) << 4);
        #pragma unroll
        for (int nf = 0; nf < 2; ++nf) {
          bf16x8 bfr = *(const bf16x8*)((const char*)W1 + (nf * 16 + ll) * 384 + cb);
          p1[nf] = __builtin_amdgcn_mfma_f32_16x16x32_bf16(areg[kk], bfr, p1[nf], 0, 0, 0);
        }
      }
      #pragma unroll
      for (int nf = 0; nf < 2; ++nf)
      #pragma unroll
      for (int r = 0; r < 4; ++r) {
        int mrow = wv * 16 + u * 4 + r;
        int n = nf * 16 + ll;
        float v = p1[nf][r] + fc1_b[c * 32 + n];
        float gl = v / (1.f + __expf(-1.702f * v));
        *(unsigned short*)((char*)P + mrow * 64 + ((n * 2) ^ (((mrow >> 1) & 3) << 4))) = f2bf(gl);
      }
    }
    {
      bf16x8 af2 = *(const bf16x8*)((const char*)P + (wv * 16 + ll) * 64 +
                                    ((u * 16) ^ (((ll >> 1) & 3) << 4)));
      #pragma unroll
      for (int nt = 0; nt < 12; ++nt) {
        bf16x8 bfr = *(const bf16x8*)((const char*)W2 + (nt * 16 + ll) * 64 +
                                      ((u * 16) ^ (((ll >> 1) & 3) << 4)));
        acc[nt] = __builtin_amdgcn_mfma_f32_16x16x32_bf16(af2, bfr, acc[nt], 0, 0, 0);
      }
    }
  }
  #pragma unroll
  for (int nt = 0; nt < 12; ++nt)
  #pragma unroll
  for (int r = 0; r < 4; ++r) {
    int m = m0 + wv * 16 + u * 4 + r;
    int n = nt * 16 + ll;
    size_t o = (size_t)m * 192 + n;
    out[o] = acc[nt][r] + fc2_b[n] + bf2f(x2[o]);
  }
}

// ---- depthwise 3x3 conv v3 (proven): horizontal pixel-quad ----
__global__ __launch_bounds__(256) void conv_k(
    const unsigned short* __restrict__ x1b, const float* __restrict__ wT,
    const float* __restrict__ bnsc, const float* __restrict__ bnsh,
    const float* __restrict__ g2, const float* __restrict__ b2,
    unsigned short* __restrict__ x2, unsigned short* __restrict__ h2)
{
  const int bid = blockIdx.x;
  const int swz = (bid & 7) * 784 + (bid >> 3);
  const int grp = threadIdx.x >> 6, l = threadIdx.x & 63;
  const int qq = swz * 4 + grp;
  const int b = qq / 784, rem = qq % 784;
  const int pix0 = rem * 4;
  const int i = pix0 / 56, j = pix0 % 56;
  const bool act = l < 48;
  const int c = l * 4;
  float4 a[4];
  #pragma unroll
  for (int p = 0; p < 4; ++p) a[p] = make_float4(0.f, 0.f, 0.f, 0.f);
  if (act) {
    #pragma unroll
    for (int di = -1; di <= 1; ++di) {
      int ni = i + di;
      if (ni < 0 || ni >= 56) continue;
      #pragma unroll
      for (int djx = 0; djx < 6; ++djx) {
        int nj = j - 1 + djx;
        float4 vv = make_float4(0.f, 0.f, 0.f, 0.f);
        if (nj >= 0 && nj < 56) {
          ushort4 sv = *(const ushort4*)&x1b[((size_t)b * LTOT + ni * 56 + nj) * DIMC + c];
          vv.x = bf2f(sv.x); vv.y = bf2f(sv.y); vv.z = bf2f(sv.z); vv.w = bf2f(sv.w);
        }
        #pragma unroll
        for (int p = 0; p < 4; ++p) {
          int dj = djx - p;
          if (dj >= 0 && dj <= 2) {
            float4 w = *(const float4*)&wT[((di + 1) * 3 + dj) * DIMC + c];
            a[p].x += vv.x * w.x; a[p].y += vv.y * w.y;
            a[p].z += vv.z * w.z; a[p].w += vv.w * w.w;
          }
        }
      }
    }
    float4 s4 = *(const float4*)&bnsc[c];
    float4 h4 = *(const float4*)&bnsh[c];
    #pragma unroll
    for (int p = 0; p < 4; ++p) {
      a[p].x = a[p].x * s4.x + h4.x; a[p].y = a[p].y * s4.y + h4.y;
      a[p].z = a[p].z * s4.z + h4.z; a[p].w = a[p].w * s4.w + h4.w;
      ushort4 xv;
      xv.x = f2bf(a[p].x); xv.y = f2bf(a[p].y); xv.z = f2bf(a[p].z); xv.w = f2bf(a[p].w);
      *(ushort4*)&x2[((size_t)b * LTOT + i * 56 + j + p) * DIMC + c] = xv;
    }
  }
  #pragma unroll
  for (int p = 0; p < 4; ++p) {
    float s = act ? a[p].x + a[p].y + a[p].z + a[p].w : 0.f;
    float ss = act ? a[p].x * a[p].x + a[p].y * a[p].y + a[p].z * a[p].z + a[p].w * a[p].w : 0.f;
    #pragma unroll
    for (int off = 1; off < 64; off <<= 1) { s += __shfl_xor(s, off); ss += __shfl_xor(ss, off); }
    float mean = s * (1.f / 192.f);
    float rstd = rsqrtf(ss * (1.f / 192.f) - mean * mean + 1e-5f);
    if (act) {
      float4 gg = *(const float4*)&g2[c];
      float4 bb = *(const float4*)&b2[c];
      ushort4 ov;
      ov.x = f2bf((a[p].x - mean) * rstd * gg.x + bb.x);
      ov.y = f2bf((a[p].y - mean) * rstd * gg.y + bb.y);
      ov.z = f2bf((a[p].z - mean) * rstd * gg.z + bb.z);
      ov.w = f2bf((a[p].w - mean) * rstd * gg.w + bb.w);
      *(ushort4*)&h2[((size_t)b * LTOT + i * 56 + j + p) * DIMC + c] = ov;
    }
  }
}

extern "C" void kernel_launch(void* const* d_in, const int* in_sizes, int n_in,
                              void* d_out, int out_size, void* d_ws, size_t ws_size,
                              hipStream_t stream) {
  const float* x      = (const float*)d_in[0];
  const float* ln1_g  = (const float*)d_in[1];
  const float* ln1_b  = (const float*)d_in[2];
  const float* qkv_w  = (const float*)d_in[3];
  const float* qkv_b  = (const float*)d_in[4];
  const float* proj_w = (const float*)d_in[5];
  const float* proj_b = (const float*)d_in[6];
  const float* attn_b = (const float*)d_in[7];
  const float* conv_w = (const float*)d_in[8];
  const float* bn_g   = (const float*)d_in[9];
  const float* bn_b   = (const float*)d_in[10];
  const float* bn_m   = (const float*)d_in[11];
  const float* bn_v   = (const float*)d_in[12];
  const float* ln2_g  = (const float*)d_in[13];
  const float* ln2_b  = (const float*)d_in[14];
  const float* fc1_w  = (const float*)d_in[15];
  const float* fc1_b  = (const float*)d_in[16];
  const float* fc2_w  = (const float*)d_in[17];
  const float* fc2_b  = (const float*)d_in[18];
  float* out = (float*)d_out;

  // workspace (155,189,248 B total — proven size):
  //  WREG [0,1MiB): converted weights
  //  A [1MiB, +115,605,504): qkv bf16 [M][576] -> (x2 @A+0, h2 @A+38.5MB after qkv dead)
  //  B [A_end, +38,535,168): x1b
  const size_t AOFF = 1048576, BOFF = AOFF + 115605504;
  const size_t NEEDED = BOFF + 38535168;
  if (ws_size < NEEDED) return;

  char* ws = (char*)d_ws;
  unsigned short* qkvT  = (unsigned short*)(ws);
  unsigned short* projT = (unsigned short*)(ws + 245760);
  unsigned short* fc1T  = (unsigned short*)(ws + 344064);
  unsigned short* fc2T  = (unsigned short*)(ws + 638976);
  float*          convT = (float*)(ws + 1032192);
  float*          bnsc  = (float*)(ws + 1039104);
  float*          bnsh  = (float*)(ws + 1039872);

  unsigned short* qkv = (unsigned short*)(ws + AOFF);
  unsigned short* x2  = (unsigned short*)(ws + AOFF);
  unsigned short* h2  = (unsigned short*)(ws + AOFF + 38535168);
  unsigned short* x1b = (unsigned short*)(ws + BOFF);

  prep_k<<<2024, 256, 0, stream>>>(qkv_w, proj_w, fc1_w, fc2_w, conv_w,
                                   bn_g, bn_b, bn_m, bn_v,
                                   qkvT, projT, fc1T, fc2T, convT, bnsc, bnsh);
  qkvg_k<<<1568, 256, 0, stream>>>(x, ln1_g, ln1_b, qkvT, qkv_b, qkv);
  attnp_k<<<2048, 256, 0, stream>>>(qkv, attn_b, projT, proj_b, x, x1b);
  conv_k<<<6272, 256, 0, stream>>>(x1b, convT, bnsc, bnsh, ln2_g, ln2_b, x2, h2);
  fmlp_k<<<1568, 256, 0, stream>>>(h2, fc1T, fc1_b, fc2T, fc2_b, x2, out);
}